// Round 1
// baseline (969.211 us; speedup 1.0000x reference)
//
#include <hip/hip_runtime.h>
#include <math.h>

#define DEVI __device__ __forceinline__

DEVI float bcast(float v, int l) { return __shfl(v, l, 64); }
DEVI float sigf(float v) { return 1.0f / (1.0f + __expf(-v)); }
DEVI float tanh_f(float v) {
    v = fminf(fmaxf(v, -15.0f), 15.0f);
    float e = __expf(2.0f * v);
    return (e - 1.0f) / (e + 1.0f);
}

// ---------------------------------------------------------------------------
// Kernel A: precompute (b,t)-independent tables:
//   Kkk[d][e] = k_d . k_e ; Kkb[d][e] = k_d . b_e ; Kbb[d][e] = b_d . b_e
//   beta[t] = (|bw_t|+1e-8) / sum_t(|bw_t|+1e-8)
// ---------------------------------------------------------------------------
__global__ void precompute_kernel(const float* __restrict__ Kg, const float* __restrict__ Bg,
                                  const float* __restrict__ betaw,
                                  float* __restrict__ Kkk, float* __restrict__ Kkb,
                                  float* __restrict__ Kbb, float* __restrict__ beta) {
    int tid = threadIdx.x;
    for (int job = tid; job < 4800; job += 256) {
        int m = job / 1600;
        int r = job - m * 1600;
        int d = r / 40;
        int e = r - d * 40;
        const float* A = (m == 2) ? Bg : Kg;
        const float* B = (m == 0) ? Kg : Bg;
        float s = 0.0f;
        for (int u = 0; u < 64; ++u) s += A[d * 64 + u] * B[e * 64 + u];
        float* O = (m == 0) ? Kkk : ((m == 1) ? Kkb : Kbb);
        O[d * 40 + e] = s;
    }
    __shared__ float red[256];
    float av = (tid < 128) ? (fabsf(betaw[tid]) + 1e-8f) : 0.0f;
    red[tid] = av;
    __syncthreads();
    for (int s = 128; s > 0; s >>= 1) {
        if (tid < s) red[tid] += red[tid + s];
        __syncthreads();
    }
    float tot = red[0];
    if (tid < 128) beta[tid] = av / tot;
}

// ---------------------------------------------------------------------------
// Kernel B: one LSTM layer (Keras gate order i,f,g,o), one WG per batch row.
// Weight columns in VGPRs; x_t / h broadcast via readlane; gates through LDS.
// ---------------------------------------------------------------------------
template <int DIN>
__launch_bounds__(256, 1)
__global__ void lstm_kernel(const float* __restrict__ xin, const float* __restrict__ W,
                            const float* __restrict__ U, const float* __restrict__ bvec,
                            float* __restrict__ hout) {
    int b = blockIdx.x;
    int tid = threadIdx.x;
    int lane = tid & 63;
    float wcol[DIN];
    float ucol[64];
#pragma unroll
    for (int d = 0; d < DIN; ++d) wcol[d] = W[d * 256 + tid];
#pragma unroll
    for (int k = 0; k < 64; ++k) ucol[k] = U[k * 256 + tid];
    float bj = bvec[tid];

    __shared__ float h_lds[64];
    __shared__ float a_lds[256];
    if (tid < 64) h_lds[tid] = 0.0f;
    float c = 0.0f;
    __syncthreads();

    const float* xb = xin + (size_t)b * 128 * DIN;
    for (int t = 0; t < 128; ++t) {
        int li = (lane < DIN) ? lane : 0;
        float xv = xb[t * DIN + li];
        if (lane >= DIN) xv = 0.0f;
        float vh = h_lds[lane];
        float acc = bj;
#pragma unroll
        for (int d = 0; d < DIN; ++d) acc = fmaf(bcast(xv, d), wcol[d], acc);
#pragma unroll
        for (int k = 0; k < 64; ++k) acc = fmaf(bcast(vh, k), ucol[k], acc);
        int g = tid >> 6;
        float a = (g == 2) ? tanh_f(acc) : sigf(acc);
        a_lds[tid] = a;
        __syncthreads();
        if (tid < 64) {
            float iv = a_lds[tid], fv = a_lds[tid + 64];
            float gv = a_lds[tid + 128], ov = a_lds[tid + 192];
            c = fmaf(fv, c, iv * gv);
            float h = ov * tanh_f(c);
            h_lds[tid] = h;
            hout[((size_t)b * 128 + t) * 64 + tid] = h;
        }
        __syncthreads();
    }
}

// ---------------------------------------------------------------------------
// Kernel C: attention. One wave per (b,t): build G from precomputed tables,
// register-resident GE solve (row-per-lane), o_hat matvec, beta-weighted sum.
// Grid = 512 (2 WGs per b, 64 t each, 16 t per wave).
// ---------------------------------------------------------------------------
__launch_bounds__(256)
__global__ void attn_kernel(const float* __restrict__ xin, const float* __restrict__ yin,
                            const float* __restrict__ Kg, const float* __restrict__ Bg,
                            const float* __restrict__ Kkkw, const float* __restrict__ Kkbw,
                            const float* __restrict__ Kbbw, const float* __restrict__ betaw,
                            float* __restrict__ out) {
    __shared__ float sm[2600 * 2 + 1640 * 3 + 256];
    float* K_l = sm;           // [40][65]
    float* B_l = K_l + 2600;   // [40][65]
    float* kk = B_l + 2600;    // [40][41]
    float* kb = kk + 1640;     // [40][41]
    float* bb = kb + 1640;     // [40][41]
    float* zred = bb + 1640;   // [256]
    int tid = threadIdx.x;
    for (int i = tid; i < 2560; i += 256) {
        int d = i >> 6, u = i & 63;
        K_l[d * 65 + u] = Kg[i];
        B_l[d * 65 + u] = Bg[i];
    }
    for (int i = tid; i < 1600; i += 256) {
        int d = i / 40, e = i - d * 40;
        kk[d * 41 + e] = Kkkw[i];
        kb[d * 41 + e] = Kkbw[i];
        bb[d * 41 + e] = Kbbw[i];
    }
    __syncthreads();

    int b = blockIdx.x >> 1;
    int hb = blockIdx.x & 1;
    int wv = tid >> 6;
    int lane = tid & 63;
    int rl = (lane < 40) ? lane : 39;  // clamped row index (lanes 40-63 idle dup)
    const float* Krow = K_l + rl * 65;
    const float* Brow = B_l + rl * 65;
    const float* kkrow = kk + rl * 41;
    const float* kbrow = kb + rl * 41;
    const float* bbrow = bb + rl * 41;

    float zacc = 0.0f;
    int t0 = hb * 64 + wv * 16;
    for (int it = 0; it < 16; ++it) {
        int t = t0 + it;
        size_t bt = (size_t)b * 128 + t;
        float xv = xin[bt * 40 + rl];
        if (lane >= 40) xv = 0.0f;
        float yv = yin[bt * 64 + lane];
        float betat = betaw[t];

        // t1 = K y, t2 = B y  (lane = row d)
        float t1 = 0.0f, t2 = 0.0f;
#pragma unroll
        for (int u = 0; u < 64; ++u) {
            float sy = bcast(yv, u);
            t1 = fmaf(Krow[u], sy, t1);
            t2 = fmaf(Brow[u], sy, t2);
        }

        // Augmented system A = [G | XTy], row per lane
        float A[41];
        A[40] = fmaf(xv, t1, t2);
#pragma unroll
        for (int e = 0; e < 40; ++e) {
            float sxe = bcast(xv, e);
            float f1 = fmaf(sxe, kkrow[e], kbrow[e]);
            float f2 = fmaf(sxe, kb[e * 41 + rl], bbrow[e]);
            A[e] = fmaf(xv, f1, f2);
        }

        // GE forward elimination (no pivoting: G is PD Gram)
#pragma unroll
        for (int k = 0; k < 39; ++k) {
            float piv = bcast(A[k], k);
            float ninv = -1.0f / piv;
            float m = (lane > k) ? A[k] * ninv : 0.0f;
#pragma unroll
            for (int j = k + 1; j <= 40; ++j) {
                float r = bcast(A[j], k);
                A[j] = fmaf(m, r, A[j]);
            }
        }

        // Back substitution
        float alpha = 0.0f;
        float acc = A[40];
#pragma unroll
        for (int k = 39; k >= 0; --k) {
            float num = bcast(acc, k);
            float den = bcast(A[k], k);
            float xk = num / den;
            if (lane == k) alpha = xk;
            acc = fmaf(-xk, A[k], acc);
        }

        // o_hat[u] = sum_d (alpha_d x_d) K[d][u] + alpha_d B[d][u]   (lane = u)
        float w = alpha * xv;
        float oh = 0.0f;
#pragma unroll
        for (int d = 0; d < 40; ++d) {
            float sw = bcast(w, d);
            float sa = bcast(alpha, d);
            oh = fmaf(sw, K_l[d * 65 + lane], oh);
            oh = fmaf(sa, B_l[d * 65 + lane], oh);
        }
        zacc = fmaf(betat, oh, zacc);
    }

    zred[tid] = zacc;
    __syncthreads();
    if (tid < 64) {
        float s = (zred[tid] + zred[tid + 64]) + (zred[tid + 128] + zred[tid + 192]);
        atomicAdd(&out[b * 64 + tid], s);  // exactly 2 adds per cell -> deterministic
    }
}

// ---------------------------------------------------------------------------
extern "C" void kernel_launch(void* const* d_in, const int* in_sizes, int n_in,
                              void* d_out, int out_size, void* d_ws, size_t ws_size,
                              hipStream_t stream) {
    const float* x  = (const float*)d_in[0];
    const float* W0 = (const float*)d_in[1];
    const float* U0 = (const float*)d_in[2];
    const float* b0 = (const float*)d_in[3];
    const float* W1 = (const float*)d_in[4];
    const float* U1 = (const float*)d_in[5];
    const float* b1 = (const float*)d_in[6];
    const float* Kg = (const float*)d_in[7];
    const float* Bg = (const float*)d_in[8];
    const float* bw = (const float*)d_in[9];
    float* out = (float*)d_out;

    float* h0   = (float*)d_ws;              // 256*128*64 = 2,097,152 f32
    float* y    = h0 + 256 * 128 * 64;       // 2,097,152 f32
    float* Kkk  = y + 256 * 128 * 64;        // 1600
    float* Kkb  = Kkk + 1600;                // 1600
    float* Kbb  = Kkb + 1600;                // 1600
    float* beta = Kbb + 1600;                // 128

    hipMemsetAsync(d_out, 0, (size_t)out_size * sizeof(float), stream);
    precompute_kernel<<<1, 256, 0, stream>>>(Kg, Bg, bw, Kkk, Kkb, Kbb, beta);
    lstm_kernel<40><<<256, 256, 0, stream>>>(x, W0, U0, b0, h0);
    lstm_kernel<64><<<256, 256, 0, stream>>>(h0, W1, U1, b1, y);
    attn_kernel<<<512, 256, 0, stream>>>(x, y, Kg, Bg, Kkk, Kkb, Kbb, beta, out);
}